// Round 4
// baseline (250.346 us; speedup 1.0000x reference)
//
#include <hip/hip_runtime.h>

// Problem constants (B,C,H,W) = (4,64,512,512), labels in [0,1024)
#define NB 4
#define NC 64
#define HW (512*512)
#define NSEG 1024
#define BK (NB*NSEG)          // 4096 segments total
#define CG 16                 // channels per group
#define NCG (NC/CG)           // 4 channel groups
#define TBL (NSEG*CG)         // 16384 words per block table

// k_accum geometry: 512 blocks of 512 thr, each owns 8192 px of one (b,cg)
#define ACHUNKS 32
#define ACHUNK_PIX (HW/ACHUNKS)   // 8192 = 4 iters * 512 thr * 4 px
// k_apply geometry: 512 blocks of 1024 thr, each owns 8192 px of one (b,cg)
#define PCHUNKS 32
#define PCHUNK_PIX (HW/PCHUNKS)

// fixed-point scale: LDS + partials at 2^12
#define SCALE_LDS 4096.0f
#define INV_LDS   (1.0f/4096.0f)

// workspace layout in 32-bit words
#define OFF_CNT    0                  // int[BK] = 4096
#define OFF_MAX    BK                 // int[1]
#define ZERO_WORDS (BK + 1)
#define OFF_SCALED 8192               // float[BK*NC] = 262144
#define OFF_PART   270336             // int[512*TBL] = 8388608 (32 MB)

#define WEIGHT 0.1f
#define EPSV   1e-5f

__global__ void k_zero(unsigned int* __restrict__ ws) {
    int i = blockIdx.x * blockDim.x + threadIdx.x;
    if (i < ZERO_WORDS) ws[i] = 0u;
}

// Per-block label histogram + max. grid = NB*128 blocks of 256 threads.
__global__ void k_hist(const int* __restrict__ sup, int* __restrict__ ws) {
    __shared__ int hist[NSEG];
    __shared__ int bmax;
    const int tid = threadIdx.x;
    for (int i = tid; i < NSEG; i += 256) hist[i] = 0;
    if (tid == 0) bmax = 0;
    __syncthreads();

    const int bid   = blockIdx.x;
    const int b     = bid >> 7;
    const int chunk = bid & 127;
    const int4* base = (const int4*)(sup + (size_t)b * HW + chunk * 2048);

    int lmax = 0;
    #pragma unroll
    for (int it = 0; it < 2; ++it) {
        int4 l4 = base[it * 256 + tid];
        atomicAdd(&hist[l4.x], 1);
        atomicAdd(&hist[l4.y], 1);
        atomicAdd(&hist[l4.z], 1);
        atomicAdd(&hist[l4.w], 1);
        lmax = max(lmax, max(max(l4.x, l4.y), max(l4.z, l4.w)));
    }
    atomicMax(&bmax, lmax);
    __syncthreads();

    int* counts = ws + OFF_CNT;
    for (int i = tid; i < NSEG; i += 256) {
        int h = hist[i];
        if (h) atomicAdd(&counts[b * NSEG + i], h);
    }
    if (tid == 0) atomicMax(&ws[OFF_MAX], bmax);
}

__device__ __forceinline__ int f2fix(float x) {
    return (int)__builtin_rintf(x * SCALE_LDS);
}

// --- k_accum helpers ---
#define ATOM4I(Lv, cc, V) { \
    atomicAdd(&tbl[(Lv).x * CG + (((cc) + (Lv).x) & 15)], f2fix((V).x)); \
    atomicAdd(&tbl[(Lv).y * CG + (((cc) + (Lv).y) & 15)], f2fix((V).y)); \
    atomicAdd(&tbl[(Lv).z * CG + (((cc) + (Lv).z) & 15)], f2fix((V).z)); \
    atomicAdd(&tbl[(Lv).w * CG + (((cc) + (Lv).w) & 15)], f2fix((V).w)); }

#define LOADB(buf, it, half) { \
    _Pragma("unroll") \
    for (int c = 0; c < 8; ++c) \
        buf[c] = *(const float4*)(ib + (size_t)((half)*8 + c) * HW + (it)*2048); }

#define CONSB(buf, Lv, half) { \
    _Pragma("unroll") \
    for (int c = 0; c < 8; ++c) ATOM4I(Lv, (half)*8 + c, buf[c]); }

// Segment-sum accumulation, int fixed-point LDS table (native ds_add_u32).
// grid = NB*NCG*ACHUNKS = 512 blocks of 512 threads; 2 blocks/CU, 128KB LDS.
// Table [NSEG][CG] int, swizzled slot: l*CG + ((c+l)&15).
// Flush: NO global atomics — each block streams its raw table to a private
// partial slice part[bid][TBL] with coalesced int4 stores.
__global__ __launch_bounds__(512, 4)
void k_accum(const float* __restrict__ inp, const int* __restrict__ sup,
             int* __restrict__ ws) {
    __shared__ int tbl[TBL];
    const int tid = threadIdx.x;
    const int bid = blockIdx.x;
    const int chunk = bid & (ACHUNKS - 1);
    const int cgb   = bid >> 5;
    const int cg    = cgb & 3;
    const int b     = cgb >> 2;

    for (int i = tid; i < TBL; i += 512) tbl[i] = 0;
    __syncthreads();

    const int pbase = chunk * ACHUNK_PIX;
    const int4* sup4 = (const int4*)(sup + (size_t)b * HW + pbase) + tid;
    const float* ib  = inp + ((size_t)(b * NC + cg * CG)) * HW + pbase + tid * 4;

    const int4 L0 = sup4[0];
    const int4 L1 = sup4[512];
    const int4 L2 = sup4[1024];
    const int4 L3 = sup4[1536];

    float4 A[8], B[8];
    LOADB(A, 0, 0); LOADB(B, 0, 1);
    CONSB(A, L0, 0); LOADB(A, 1, 0);
    CONSB(B, L0, 1); LOADB(B, 1, 1);
    CONSB(A, L1, 0); LOADB(A, 2, 0);
    CONSB(B, L1, 1); LOADB(B, 2, 1);
    CONSB(A, L2, 0); LOADB(A, 3, 0);
    CONSB(B, L2, 1); LOADB(B, 3, 1);
    CONSB(A, L3, 0);
    CONSB(B, L3, 1);

    __syncthreads();
    int4* part = (int4*)(ws + OFF_PART + (size_t)bid * TBL);
    #pragma unroll
    for (int it = 0; it < TBL / (512 * 4); ++it)   // 8 iters
        part[it * 512 + tid] = *(const int4*)&tbl[(it * 512 + tid) * 4];
}

// Reduce 32 chunk-partials per (b,cg,seg,c16), apply mean/weight/validity.
// grid = BK*NC/256 = 1024 blocks of 256. idx = (b*1024+seg)*64 + cg*16 + c16.
__global__ void k_reduce(const int* __restrict__ wsi, float* __restrict__ wsf) {
    const int idx = blockIdx.x * 256 + threadIdx.x;
    const int s   = idx >> 6;          // b*1024+seg
    const int b   = s >> 10;
    const int seg = s & (NSEG - 1);
    const int c   = idx & 63;
    const int cg  = c >> 4;
    const int c16 = c & 15;
    const int e   = seg * CG + ((c16 + seg) & 15);   // swizzled table slot
    const int cgb = b * NCG + cg;

    const int* base = wsi + OFF_PART + (size_t)cgb * ACHUNKS * TBL + e;
    int acc = 0;
    #pragma unroll
    for (int ch = 0; ch < ACHUNKS; ++ch) acc += base[(size_t)ch * TBL];

    const int   maxele = wsi[OFF_MAX];
    const float cnt    = (float)wsi[OFF_CNT + s];
    const float sumf   = (float)acc * INV_LDS;
    const float m      = WEIGHT * sumf / (cnt + EPSV);
    wsf[OFF_SCALED + idx] = (seg < maxele) ? m : 0.f;
}

// --- k_apply helpers ---
#define PLOAD(buf, it, half) { \
    _Pragma("unroll") \
    for (int c = 0; c < 8; ++c) \
        buf[c] = *(const float4*)(ib + (size_t)((half)*8 + c) * HW + (it)*4096); }

#define PCONS(buf, it, half) { \
    _Pragma("unroll") \
    for (int c = 0; c < 8; ++c) { \
        float4 v = buf[c]; \
        const int4 Lv = L[(it)]; \
        const int cc = (half)*8 + c; \
        v.x += tbl[Lv.x * CG + ((cc + Lv.x) & 15)]; \
        v.y += tbl[Lv.y * CG + ((cc + Lv.y) & 15)]; \
        v.z += tbl[Lv.z * CG + ((cc + Lv.z) & 15)]; \
        v.w += tbl[Lv.w * CG + ((cc + Lv.w) & 15)]; \
        *(float4*)(ob + (size_t)cc * HW + (it)*4096) = v; } }

// Apply: out = inp + scaled[seg][c]. grid = NB*NCG*PCHUNKS = 512 blocks.
__global__ __launch_bounds__(1024, 4)
void k_apply(const float* __restrict__ inp, const int* __restrict__ sup,
             const float* __restrict__ ws, float* __restrict__ out) {
    __shared__ float tbl[TBL];
    const int tid = threadIdx.x;
    const int bid = blockIdx.x;
    const int chunk = bid & (PCHUNKS - 1);
    const int cgb   = bid >> 5;
    const int cg    = cgb & 3;
    const int b     = cgb >> 2;

    const float* scaled = ws + OFF_SCALED;
    for (int e = tid; e < TBL; e += 1024) {
        const int seg = e >> 4;
        const int j   = e & 15;
        const int c16 = (j - seg) & 15;
        tbl[e] = scaled[((size_t)(b * NSEG + seg)) * NC + cg * CG + c16];
    }

    const int pbase = chunk * PCHUNK_PIX;
    const int* supb = sup + (size_t)b * HW + pbase + tid * 4;
    const float* ib = inp + ((size_t)(b * NC + cg * CG)) * HW + pbase + tid * 4;
    float* ob       = out + ((size_t)(b * NC + cg * CG)) * HW + pbase + tid * 4;

    int4 L[2];
    L[0] = *(const int4*)(supb);
    L[1] = *(const int4*)(supb + 4096);

    float4 va[8], vb[8];
    PLOAD(va, 0, 0); PLOAD(vb, 0, 1);
    __syncthreads();   // tbl staged
    PCONS(va, 0, 0); PLOAD(va, 1, 0);
    PCONS(vb, 0, 1); PLOAD(vb, 1, 1);
    PCONS(va, 1, 0);
    PCONS(vb, 1, 1);
}

extern "C" void kernel_launch(void* const* d_in, const int* in_sizes, int n_in,
                              void* d_out, int out_size, void* d_ws, size_t ws_size,
                              hipStream_t stream) {
    const float* inp = (const float*)d_in[0];
    const int*   sup = (const int*)d_in[1];
    float* out = (float*)d_out;

    k_zero<<<(ZERO_WORDS + 255) / 256, 256, 0, stream>>>((unsigned int*)d_ws);
    k_hist<<<NB * 128, 256, 0, stream>>>(sup, (int*)d_ws);
    k_accum<<<NB * NCG * ACHUNKS, 512, 0, stream>>>(inp, sup, (int*)d_ws);
    k_reduce<<<(BK * NC) / 256, 256, 0, stream>>>((const int*)d_ws, (float*)d_ws);
    k_apply<<<NB * NCG * PCHUNKS, 1024, 0, stream>>>(inp, sup, (const float*)d_ws, out);
}

// Round 5
// 194.551 us; speedup vs baseline: 1.2868x; 1.2868x over previous
//
#include <hip/hip_runtime.h>

// Problem constants (B,C,H,W) = (4,64,512,512), labels in [0,1024)
#define NB 4
#define NC 64
#define HW (512*512)
#define NSEG 1024
#define BK (NB*NSEG)
#define CG 16                  // channels per accum block
#define NCG (NC/CG)            // 4
#define NPAIR 8                // channel pairs per accum block
#define TBLW (NSEG*CG)         // 16384 32-bit words per block table

#define ACHUNKS 32
#define ACHUNK_PIX (HW/ACHUNKS)   // 8192 px per accum block
#define PCHUNKS 32
#define PCHUNK_PIX (HW/PCHUNKS)

// fixed point: scale 2^12, per-addend bias 2^16 (keeps both u64 halves positive)
#define SCALE_LDS 4096.0f
#define INV_LDS   (1.0f/4096.0f)
#define BIASF     65536.5f     // +0.5 => round-half-up under truncating cvt

// workspace layout in 32-bit words (all regions fully rewritten every call)
#define OFF_PART   0                         // int[512*TBLW] = 32 MB
#define OFF_HIST   (512*TBLW)                // int[128*NSEG] = 512 KB
#define OFF_MAXP   (OFF_HIST + 128*NSEG)     // int[128]
#define OFF_SCALED (OFF_MAXP + 128)          // float[BK*NC] = 1 MB

#define WEIGHT 0.1f
#define EPSV   1e-5f

__device__ __forceinline__ int f2b(float x) {
    return (int)__builtin_fmaf(x, SCALE_LDS, BIASF);   // biased, positive
}
__device__ __forceinline__ unsigned long long pk(int lo, int hi) {
    return (unsigned long long)(unsigned)lo |
           ((unsigned long long)(unsigned)hi << 32);
}

// --- k_accum helpers ---
#define PATOM(Lv, p, VL, VH) { \
    atomicAdd(&tbl[(Lv).x * NPAIR + (((p) + (Lv).x) & 7)], pk(f2b((VL).x), f2b((VH).x))); \
    atomicAdd(&tbl[(Lv).y * NPAIR + (((p) + (Lv).y) & 7)], pk(f2b((VL).y), f2b((VH).y))); \
    atomicAdd(&tbl[(Lv).z * NPAIR + (((p) + (Lv).z) & 7)], pk(f2b((VL).z), f2b((VH).z))); \
    atomicAdd(&tbl[(Lv).w * NPAIR + (((p) + (Lv).w) & 7)], pk(f2b((VL).w), f2b((VH).w))); }

#define LOADB(buf, it, half) { \
    _Pragma("unroll") \
    for (int c = 0; c < 8; ++c) \
        buf[c] = *(const float4*)(ib + (size_t)((half)*8 + c) * HW + (it)*2048); }

#define CONSB(buf, Lv, half) { \
    PATOM(Lv, (half)*4 + 0, buf[0], buf[1]); \
    PATOM(Lv, (half)*4 + 1, buf[2], buf[3]); \
    PATOM(Lv, (half)*4 + 2, buf[4], buf[5]); \
    PATOM(Lv, (half)*4 + 3, buf[6], buf[7]); }

// Segment-sum accumulation with packed u64 LDS atomics (native ds_add_u64).
// grid = NB*NCG*ACHUNKS = 512 blocks of 512 threads; 2 blocks/CU (~68KB LDS).
// Table [NSEG][NPAIR] u64, swizzled pair-slot: l*8 + ((p+l)&7).
// cg==0 blocks also histogram labels + track max (folded k_hist).
__global__ __launch_bounds__(512, 4)
void k_accum(const float* __restrict__ inp, const int* __restrict__ sup,
             int* __restrict__ ws) {
    __shared__ __align__(16) unsigned long long tbl[NSEG * NPAIR];  // 64 KB
    __shared__ int hist[NSEG];                                      // 4 KB
    __shared__ int bmax;
    const int tid = threadIdx.x;
    const int bid = blockIdx.x;
    const int chunk = bid & (ACHUNKS - 1);
    const int cgb   = bid >> 5;
    const int cg    = cgb & 3;
    const int b     = cgb >> 2;

    {
        int4 z = {0, 0, 0, 0};
        int4* t4 = (int4*)tbl;
        #pragma unroll
        for (int i = 0; i < 8; ++i) t4[i * 512 + tid] = z;
    }
    if (cg == 0) {
        for (int i = tid; i < NSEG; i += 512) hist[i] = 0;
        if (tid == 0) bmax = 0;
    }
    __syncthreads();

    const int pbase = chunk * ACHUNK_PIX;
    const int4* sup4 = (const int4*)(sup + (size_t)b * HW + pbase) + tid;
    const float* ib  = inp + ((size_t)(b * NC + cg * CG)) * HW + pbase + tid * 4;

    const int4 L0 = sup4[0];
    const int4 L1 = sup4[512];
    const int4 L2 = sup4[1024];
    const int4 L3 = sup4[1536];

    if (cg == 0) {   // folded histogram + max (block-uniform branch)
        atomicAdd(&hist[L0.x], 1); atomicAdd(&hist[L0.y], 1);
        atomicAdd(&hist[L0.z], 1); atomicAdd(&hist[L0.w], 1);
        atomicAdd(&hist[L1.x], 1); atomicAdd(&hist[L1.y], 1);
        atomicAdd(&hist[L1.z], 1); atomicAdd(&hist[L1.w], 1);
        atomicAdd(&hist[L2.x], 1); atomicAdd(&hist[L2.y], 1);
        atomicAdd(&hist[L2.z], 1); atomicAdd(&hist[L2.w], 1);
        atomicAdd(&hist[L3.x], 1); atomicAdd(&hist[L3.y], 1);
        atomicAdd(&hist[L3.z], 1); atomicAdd(&hist[L3.w], 1);
        int m01 = max(max(L0.x, L0.y), max(L0.z, L0.w));
        int m23 = max(max(L1.x, L1.y), max(L1.z, L1.w));
        int m45 = max(max(L2.x, L2.y), max(L2.z, L2.w));
        int m67 = max(max(L3.x, L3.y), max(L3.z, L3.w));
        atomicMax(&bmax, max(max(m01, m23), max(m45, m67)));
    }

    float4 A[8], B[8];
    LOADB(A, 0, 0); LOADB(B, 0, 1);
    CONSB(A, L0, 0); LOADB(A, 1, 0);
    CONSB(B, L0, 1); LOADB(B, 1, 1);
    CONSB(A, L1, 0); LOADB(A, 2, 0);
    CONSB(B, L1, 1); LOADB(B, 2, 1);
    CONSB(A, L2, 0); LOADB(A, 3, 0);
    CONSB(B, L2, 1); LOADB(B, 3, 1);
    CONSB(A, L3, 0);
    CONSB(B, L3, 1);

    __syncthreads();
    // stream raw table (still biased fixed-point) to private partial slice
    int4* part = (int4*)(ws + OFF_PART + (size_t)bid * TBLW);
    const int4* t4 = (const int4*)tbl;
    #pragma unroll
    for (int it = 0; it < 8; ++it)
        part[it * 512 + tid] = t4[it * 512 + tid];
    if (cg == 0) {
        int4* hd = (int4*)(ws + OFF_HIST + (size_t)(b * ACHUNKS + chunk) * NSEG);
        if (tid < 256) hd[tid] = ((const int4*)hist)[tid];
        if (tid == 0) ws[OFF_MAXP + b * ACHUNKS + chunk] = bmax;
    }
}

// Reduce 32 chunk partials, remove bias via counts, apply mean/weight/validity.
// grid = BK*NC/256 = 1024 blocks of 256. idx -> (b,seg,c).
__global__ void k_reduce(const int* __restrict__ wsi, float* __restrict__ wsf) {
    __shared__ int smax;
    const int tid = threadIdx.x;
    const int idx = blockIdx.x * 256 + tid;
    if (tid == 0) smax = 0;
    __syncthreads();
    if (tid < 128) atomicMax(&smax, wsi[OFF_MAXP + tid]);

    const int s    = idx >> 6;           // b*1024+seg
    const int b    = s >> 10;
    const int seg  = s & (NSEG - 1);
    const int c    = idx & 63;
    const int cg   = c >> 4;
    const int c16  = c & 15;
    const int pair = c16 >> 1;
    const int hi   = c16 & 1;
    const int widx = (seg * NPAIR + ((pair + seg) & 7)) * 2 + hi;

    const int* pb = wsi + OFF_PART + (size_t)((b * NCG + cg) * ACHUNKS) * TBLW + widx;
    long long acc = 0;
    #pragma unroll
    for (int ch = 0; ch < ACHUNKS; ++ch)
        acc += (long long)(unsigned)pb[(size_t)ch * TBLW];

    const int* hb = wsi + OFF_HIST + b * ACHUNKS * NSEG + seg;
    int cnt = 0;
    #pragma unroll
    for (int ch = 0; ch < ACHUNKS; ++ch) cnt += hb[ch * NSEG];

    acc -= ((long long)cnt) << 16;       // remove per-addend bias exactly

    __syncthreads();
    const int maxele = smax;
    const float m = WEIGHT * ((float)acc * INV_LDS) / ((float)cnt + EPSV);
    wsf[OFF_SCALED + idx] = (seg < maxele) ? m : 0.f;
}

// --- k_apply helpers ---
#define PLOAD(buf, it, half) { \
    _Pragma("unroll") \
    for (int c = 0; c < 8; ++c) \
        buf[c] = *(const float4*)(ib + (size_t)((half)*8 + c) * HW + (it)*4096); }

#define PCONS(buf, it, half) { \
    _Pragma("unroll") \
    for (int c = 0; c < 8; ++c) { \
        float4 v = buf[c]; \
        const int4 Lv = L[(it)]; \
        const int cc = (half)*8 + c; \
        v.x += tblf[Lv.x * CG + ((cc + Lv.x) & 15)]; \
        v.y += tblf[Lv.y * CG + ((cc + Lv.y) & 15)]; \
        v.z += tblf[Lv.z * CG + ((cc + Lv.z) & 15)]; \
        v.w += tblf[Lv.w * CG + ((cc + Lv.w) & 15)]; \
        *(float4*)(ob + (size_t)cc * HW + (it)*4096) = v; } }

// Apply: out = inp + scaled[seg][c]. grid = NB*NCG*PCHUNKS = 512 blocks.
__global__ __launch_bounds__(1024, 4)
void k_apply(const float* __restrict__ inp, const int* __restrict__ sup,
             const float* __restrict__ ws, float* __restrict__ out) {
    __shared__ float tblf[TBLW];
    const int tid = threadIdx.x;
    const int bid = blockIdx.x;
    const int chunk = bid & (PCHUNKS - 1);
    const int cgb   = bid >> 5;
    const int cg    = cgb & 3;
    const int b     = cgb >> 2;

    const float* scaled = ws + OFF_SCALED;
    for (int e = tid; e < TBLW; e += 1024) {
        const int seg = e >> 4;
        const int j   = e & 15;
        const int c16 = (j - seg) & 15;
        tblf[e] = scaled[((size_t)(b * NSEG + seg)) * NC + cg * CG + c16];
    }

    const int pbase = chunk * PCHUNK_PIX;
    const int* supb = sup + (size_t)b * HW + pbase + tid * 4;
    const float* ib = inp + ((size_t)(b * NC + cg * CG)) * HW + pbase + tid * 4;
    float* ob       = out + ((size_t)(b * NC + cg * CG)) * HW + pbase + tid * 4;

    int4 L[2];
    L[0] = *(const int4*)(supb);
    L[1] = *(const int4*)(supb + 4096);

    float4 va[8], vb[8];
    PLOAD(va, 0, 0); PLOAD(vb, 0, 1);
    __syncthreads();   // tblf staged
    PCONS(va, 0, 0); PLOAD(va, 1, 0);
    PCONS(vb, 0, 1); PLOAD(vb, 1, 1);
    PCONS(va, 1, 0);
    PCONS(vb, 1, 1);
}

extern "C" void kernel_launch(void* const* d_in, const int* in_sizes, int n_in,
                              void* d_out, int out_size, void* d_ws, size_t ws_size,
                              hipStream_t stream) {
    const float* inp = (const float*)d_in[0];
    const int*   sup = (const int*)d_in[1];
    float* out = (float*)d_out;

    k_accum<<<NB * NCG * ACHUNKS, 512, 0, stream>>>(inp, sup, (int*)d_ws);
    k_reduce<<<(BK * NC) / 256, 256, 0, stream>>>((const int*)d_ws, (float*)d_ws);
    k_apply<<<NB * NCG * PCHUNKS, 1024, 0, stream>>>(inp, sup, (const float*)d_ws, out);
}

// Round 7
// 145.752 us; speedup vs baseline: 1.7176x; 1.3348x over previous
//
#include <hip/hip_runtime.h>

// Problem constants (B,C,H,W) = (4,64,512,512), labels in [0,1024)
#define NB 4
#define NC 64
#define HW (512*512)
#define NSEG 1024
#define BK (NB*NSEG)
#define CG 16                  // channels per accum/apply block
#define NCG (NC/CG)            // 4
#define NPAIR 8                // channel pairs per accum block
#define TBLW (NSEG*CG)         // 16384 32-bit words per block table

#define ACHUNKS 32
#define ACHUNK_PIX (HW/ACHUNKS)   // 8192 px per accum block
#define PCHUNKS 32
#define PCHUNK_PIX (HW/PCHUNKS)

// fixed point: scale 2^12, per-addend bias 2^16 (keeps both u64 halves positive)
#define SCALE_LDS 4096.0f
#define INV_LDS   (1.0f/4096.0f)
#define BIASF     65536.5f     // +0.5 => round-half-up under truncating cvt

// workspace layout in 32-bit words (all regions fully rewritten every call)
#define OFF_PART   0                         // int[512*TBLW] = 32 MB
#define OFF_HIST   (512*TBLW)                // int[128*NSEG] = 512 KB
#define OFF_MAXP   (OFF_HIST + 128*NSEG)     // int[128]
#define OFF_SCALED (OFF_MAXP + 128)          // float[BK*NC] = 1 MB

#define WEIGHT 0.1f
#define EPSV   1e-5f

// clang-native vector types: __builtin_nontemporal_* rejects HIP_vector_type
typedef int   i32x4 __attribute__((ext_vector_type(4)));
typedef float f32x4 __attribute__((ext_vector_type(4)));

__device__ __forceinline__ int f2b(float x) {
    return (int)__builtin_fmaf(x, SCALE_LDS, BIASF);   // biased, positive
}
__device__ __forceinline__ unsigned long long pk(int lo, int hi) {
    return (unsigned long long)(unsigned)lo |
           ((unsigned long long)(unsigned)hi << 32);
}

// --- k_accum helpers ---
// pair-slot swizzle: l*8 + ((p + (l>>1)) & 7)  -> random l spreads same-parity
// lanes over all 8 slots of the 16-bank half (was (p+l)&7: only 4).
#define PATOM(Lv, p, VL, VH) { \
    atomicAdd(&tbl[(Lv).x * NPAIR + (((p) + ((Lv).x >> 1)) & 7)], pk(f2b((VL).x), f2b((VH).x))); \
    atomicAdd(&tbl[(Lv).y * NPAIR + (((p) + ((Lv).y >> 1)) & 7)], pk(f2b((VL).y), f2b((VH).y))); \
    atomicAdd(&tbl[(Lv).z * NPAIR + (((p) + ((Lv).z >> 1)) & 7)], pk(f2b((VL).z), f2b((VH).z))); \
    atomicAdd(&tbl[(Lv).w * NPAIR + (((p) + ((Lv).w >> 1)) & 7)], pk(f2b((VL).w), f2b((VH).w))); }

#define LOADB(buf, it, half) { \
    _Pragma("unroll") \
    for (int c = 0; c < 8; ++c) \
        buf[c] = *(const float4*)(ib + (size_t)((half)*8 + c) * HW + (it)*2048); }

#define CONSB(buf, Lv, half) { \
    PATOM(Lv, (half)*4 + 0, buf[0], buf[1]); \
    PATOM(Lv, (half)*4 + 1, buf[2], buf[3]); \
    PATOM(Lv, (half)*4 + 2, buf[4], buf[5]); \
    PATOM(Lv, (half)*4 + 3, buf[6], buf[7]); }

// Segment-sum accumulation with packed u64 LDS atomics (native ds_add_u64).
// grid = NB*NCG*ACHUNKS = 512 blocks of 512 threads; 2 blocks/CU (~68KB LDS).
// cg==0 blocks also histogram labels + track max. Flush via nt stores so the
// partials don't evict inp from L3 (k_apply re-reads inp).
__global__ __launch_bounds__(512, 4)
void k_accum(const float* __restrict__ inp, const int* __restrict__ sup,
             int* __restrict__ ws) {
    __shared__ __align__(16) unsigned long long tbl[NSEG * NPAIR];  // 64 KB
    __shared__ int hist[NSEG];                                      // 4 KB
    __shared__ int bmax;
    const int tid = threadIdx.x;
    const int bid = blockIdx.x;
    const int chunk = bid & (ACHUNKS - 1);
    const int cgb   = bid >> 5;
    const int cg    = cgb & 3;
    const int b     = cgb >> 2;

    {
        i32x4 z = {0, 0, 0, 0};
        i32x4* t4 = (i32x4*)tbl;
        #pragma unroll
        for (int i = 0; i < 8; ++i) t4[i * 512 + tid] = z;
    }
    if (cg == 0) {
        for (int i = tid; i < NSEG; i += 512) hist[i] = 0;
        if (tid == 0) bmax = 0;
    }
    __syncthreads();

    const int pbase = chunk * ACHUNK_PIX;
    const int4* sup4 = (const int4*)(sup + (size_t)b * HW + pbase) + tid;
    const float* ib  = inp + ((size_t)(b * NC + cg * CG)) * HW + pbase + tid * 4;

    const int4 L0 = sup4[0];
    const int4 L1 = sup4[512];
    const int4 L2 = sup4[1024];
    const int4 L3 = sup4[1536];

    if (cg == 0) {   // folded histogram + max (block-uniform branch)
        atomicAdd(&hist[L0.x], 1); atomicAdd(&hist[L0.y], 1);
        atomicAdd(&hist[L0.z], 1); atomicAdd(&hist[L0.w], 1);
        atomicAdd(&hist[L1.x], 1); atomicAdd(&hist[L1.y], 1);
        atomicAdd(&hist[L1.z], 1); atomicAdd(&hist[L1.w], 1);
        atomicAdd(&hist[L2.x], 1); atomicAdd(&hist[L2.y], 1);
        atomicAdd(&hist[L2.z], 1); atomicAdd(&hist[L2.w], 1);
        atomicAdd(&hist[L3.x], 1); atomicAdd(&hist[L3.y], 1);
        atomicAdd(&hist[L3.z], 1); atomicAdd(&hist[L3.w], 1);
        int m01 = max(max(L0.x, L0.y), max(L0.z, L0.w));
        int m23 = max(max(L1.x, L1.y), max(L1.z, L1.w));
        int m45 = max(max(L2.x, L2.y), max(L2.z, L2.w));
        int m67 = max(max(L3.x, L3.y), max(L3.z, L3.w));
        atomicMax(&bmax, max(max(m01, m23), max(m45, m67)));
    }

    float4 A[8], B[8];
    LOADB(A, 0, 0); LOADB(B, 0, 1);
    CONSB(A, L0, 0); LOADB(A, 1, 0);
    CONSB(B, L0, 1); LOADB(B, 1, 1);
    CONSB(A, L1, 0); LOADB(A, 2, 0);
    CONSB(B, L1, 1); LOADB(B, 2, 1);
    CONSB(A, L2, 0); LOADB(A, 3, 0);
    CONSB(B, L2, 1); LOADB(B, 3, 1);
    CONSB(A, L3, 0);
    CONSB(B, L3, 1);

    __syncthreads();
    // stream raw table (biased fixed-point) to private partial slice, nt
    i32x4* part = (i32x4*)(ws + OFF_PART + (size_t)bid * TBLW);
    const i32x4* t4 = (const i32x4*)tbl;
    #pragma unroll
    for (int it = 0; it < 8; ++it)
        __builtin_nontemporal_store(t4[it * 512 + tid], &part[it * 512 + tid]);
    if (cg == 0) {
        i32x4* hd = (i32x4*)(ws + OFF_HIST + (size_t)(b * ACHUNKS + chunk) * NSEG);
        if (tid < 256) __builtin_nontemporal_store(((const i32x4*)hist)[tid], &hd[tid]);
        if (tid == 0) ws[OFF_MAXP + b * ACHUNKS + chunk] = bmax;
    }
}

// Reduce 32 chunk partials (nt loads — sole reader, don't pollute L3),
// remove bias via counts, apply mean/weight/validity.
// grid = BK*NC/256 = 1024 blocks of 256. idx -> (b,seg,c).
__global__ void k_reduce(const int* __restrict__ wsi, float* __restrict__ wsf) {
    __shared__ int smax;
    const int tid = threadIdx.x;
    const int idx = blockIdx.x * 256 + tid;
    if (tid == 0) smax = 0;
    __syncthreads();
    if (tid < 128) atomicMax(&smax, wsi[OFF_MAXP + tid]);

    const int s    = idx >> 6;           // b*1024+seg
    const int b    = s >> 10;
    const int seg  = s & (NSEG - 1);
    const int c    = idx & 63;
    const int cg   = c >> 4;
    const int c16  = c & 15;
    const int pair = c16 >> 1;
    const int hi   = c16 & 1;
    const int widx = (seg * NPAIR + ((pair + (seg >> 1)) & 7)) * 2 + hi;

    const int* pb = wsi + OFF_PART + (size_t)((b * NCG + cg) * ACHUNKS) * TBLW + widx;
    long long acc = 0;
    #pragma unroll
    for (int ch = 0; ch < ACHUNKS; ++ch)
        acc += (long long)(unsigned)__builtin_nontemporal_load(&pb[(size_t)ch * TBLW]);

    const int* hb = wsi + OFF_HIST + b * ACHUNKS * NSEG + seg;
    int cnt = 0;
    #pragma unroll
    for (int ch = 0; ch < ACHUNKS; ++ch)
        cnt += __builtin_nontemporal_load(&hb[ch * NSEG]);

    acc -= ((long long)cnt) << 16;       // remove per-addend bias exactly

    __syncthreads();
    const int maxele = smax;
    const float m = WEIGHT * ((float)acc * INV_LDS) / ((float)cnt + EPSV);
    wsf[OFF_SCALED + idx] = (seg < maxele) ? m : 0.f;
}

// --- k_apply helpers ---
#define PLOAD(buf, it, half) { \
    _Pragma("unroll") \
    for (int c = 0; c < 8; ++c) \
        buf[c] = *(const f32x4*)(ib + (size_t)((half)*8 + c) * HW + (it)*4096); }

// quad-rotated gather: channel quad q of row l lives at slot (q + (l>>1)) & 3
// (16-float rows = 64 B; (l>>1) rotation spreads same-parity lanes across all
// 4 quad-groups of the row's 16-bank half -> ~min b128 conflicts).
#define GHALF(buf, lv, h, comp) { \
    const int _bse = (lv) * CG; \
    const int _r   = (lv) >> 1; \
    const f32x4 qa = *(const f32x4*)&tblf[_bse + ((((h)*2 + 0 + _r) & 3) << 2)]; \
    const f32x4 qb = *(const f32x4*)&tblf[_bse + ((((h)*2 + 1 + _r) & 3) << 2)]; \
    buf[0].comp += qa.x; buf[1].comp += qa.y; buf[2].comp += qa.z; buf[3].comp += qa.w; \
    buf[4].comp += qb.x; buf[5].comp += qb.y; buf[6].comp += qb.z; buf[7].comp += qb.w; }

#define PCONS(buf, it, h) { \
    const int4 Lv = L[(it)]; \
    GHALF(buf, Lv.x, h, x) \
    GHALF(buf, Lv.y, h, y) \
    GHALF(buf, Lv.z, h, z) \
    GHALF(buf, Lv.w, h, w) \
    _Pragma("unroll") \
    for (int c = 0; c < 8; ++c) \
        __builtin_nontemporal_store(buf[c], (f32x4*)(ob + (size_t)((h)*8 + c) * HW + (it)*4096)); }

// Apply: out = inp + scaled[seg][c]. grid = NB*NCG*PCHUNKS = 512 blocks.
// nt stores for out: write-once data must not evict L3-resident inp.
__global__ __launch_bounds__(1024, 4)
void k_apply(const float* __restrict__ inp, const int* __restrict__ sup,
             const float* __restrict__ ws, float* __restrict__ out) {
    __shared__ float tblf[TBLW];
    const int tid = threadIdx.x;
    const int bid = blockIdx.x;
    const int chunk = bid & (PCHUNKS - 1);
    const int cgb   = bid >> 5;
    const int cg    = cgb & 3;
    const int b     = cgb >> 2;

    const float* scaled = ws + OFF_SCALED;
    for (int e = tid; e < TBLW; e += 1024) {
        const int l = e >> 4;
        const int sl = (e >> 2) & 3;
        const int j  = e & 3;
        const int q  = (sl - (l >> 1)) & 3;          // stored slot sl holds quad q
        tblf[e] = scaled[((size_t)(b * NSEG + l)) * NC + cg * CG + q * 4 + j];
    }

    const int pbase = chunk * PCHUNK_PIX;
    const int* supb = sup + (size_t)b * HW + pbase + tid * 4;
    const float* ib = inp + ((size_t)(b * NC + cg * CG)) * HW + pbase + tid * 4;
    float* ob       = out + ((size_t)(b * NC + cg * CG)) * HW + pbase + tid * 4;

    int4 L[2];
    L[0] = *(const int4*)(supb);
    L[1] = *(const int4*)(supb + 4096);

    f32x4 va[8], vb[8];
    PLOAD(va, 0, 0); PLOAD(vb, 0, 1);
    __syncthreads();   // tblf staged
    PCONS(va, 0, 0); PLOAD(va, 1, 0);
    PCONS(vb, 0, 1); PLOAD(vb, 1, 1);
    PCONS(va, 1, 0);
    PCONS(vb, 1, 1);
}

extern "C" void kernel_launch(void* const* d_in, const int* in_sizes, int n_in,
                              void* d_out, int out_size, void* d_ws, size_t ws_size,
                              hipStream_t stream) {
    const float* inp = (const float*)d_in[0];
    const int*   sup = (const int*)d_in[1];
    float* out = (float*)d_out;

    k_accum<<<NB * NCG * ACHUNKS, 512, 0, stream>>>(inp, sup, (int*)d_ws);
    k_reduce<<<(BK * NC) / 256, 256, 0, stream>>>((const int*)d_ws, (float*)d_ws);
    k_apply<<<NB * NCG * PCHUNKS, 1024, 0, stream>>>(inp, sup, (const float*)d_ws, out);
}